// Round 1
// 973.623 us; speedup vs baseline: 1.0133x; 1.0133x over previous
//
#include <hip/hip_runtime.h>
#include <hip/hip_bf16.h>
#include <stdint.h>

typedef __bf16 bf16;
typedef __bf16 bf16x8 __attribute__((ext_vector_type(8)));
typedef __bf16 bf16x4 __attribute__((ext_vector_type(4)));
typedef float  floatx4 __attribute__((ext_vector_type(4)));
typedef unsigned int uint32;

#define B_  8
#define C_  2048
#define N_  8000
#define H_  256
#define O_  1000
#define OP_ 1024   // O padded to MFMA-friendly 1024

// async global->LDS, 16B per lane; LDS dst = wave-uniform base + lane*16
__device__ __forceinline__ void gll16(const void* g, void* l) {
  __builtin_amdgcn_global_load_lds((const __attribute__((address_space(1))) void*)g,
                                   (__attribute__((address_space(3))) void*)l, 16, 0, 0);
}

// -------------------- weight pre-cast (fp32 -> bf16, W2 padded to 1024 rows) -----
// vectorized: one float4 -> bf16x4 per thread. 212992 groups = 832 blocks exactly.
__global__ __launch_bounds__(256) void castw(const float* __restrict__ W0,
                                             const float* __restrict__ W1,
                                             const float* __restrict__ W2,
                                             bf16* __restrict__ W0b,
                                             bf16* __restrict__ W1b,
                                             bf16* __restrict__ W2b) {
  int g = blockIdx.x * 256 + threadIdx.x;     // < 212992
  float4 v;
  bf16* dst;
  if (g < 131072) {                           // W0: 524288 elems
    v = ((const float4*)W0)[g];
    dst = W0b + g * 4;
  } else if (g < 147456) {                    // W1: 65536 elems
    int i = g - 131072;
    v = ((const float4*)W1)[i];
    dst = W1b + i * 4;
  } else {                                    // W2 padded: 262144 elems
    int i = g - 147456;
    int o = i >> 6, k4 = i & 63;
    if (o < O_) v = *(const float4*)(W2 + o * 256 + k4 * 4);
    else        v = make_float4(0.f, 0.f, 0.f, 0.f);
    dst = W2b + i * 4;
  }
  bf16x4 r;
  r[0] = (bf16)v.x; r[1] = (bf16)v.y; r[2] = (bf16)v.z; r[3] = (bf16)v.w;
  *(bf16x4*)dst = r;
}

// -------------------- layer 1: h1T[b][n][h] = clip(relu(W0 x + b0)) + mask -------
__global__ __launch_bounds__(256) void gemm1(const float* __restrict__ x,
                                             const bf16* __restrict__ W0b,
                                             const float* __restrict__ bias0,
                                             bf16* __restrict__ h1T,
                                             float* __restrict__ maskb) {
  __shared__ union {
    struct { bf16 A[H_ * 32]; bf16 Bt[64 * 40]; } st;
    bf16 HT[64 * 264];
  } sm;
  __shared__ float sbias[256];
  __shared__ uint32 nflag[64];

  const int tid  = threadIdx.x;
  const int wave = tid >> 6, lane = tid & 63;
  const int l16  = lane & 15, l4 = lane >> 4;
  const int n0   = blockIdx.x * 64;
  const int b    = blockIdx.y;

  sbias[tid] = bias0[tid];
  if (tid < 64) nflag[tid] = 0;

  const int kp = tid >> 4;          // 0..15 -> k-pair 2*kp
  const int n4 = (tid & 15) * 4;    // 0..60
  const float* xbase = x + (size_t)b * C_ * N_ + n0 + n4;

  floatx4 acc[4][4];
  #pragma unroll
  for (int i = 0; i < 4; ++i)
    #pragma unroll
    for (int j = 0; j < 4; ++j)
      acc[i][j] = floatx4{0.f, 0.f, 0.f, 0.f};

  uint32 fl = 0;

  for (int k0 = 0; k0 < C_; k0 += 32) {
    #pragma unroll
    for (int i = 0; i < 4; ++i) {
      int c = i * 256 + tid;
      gll16(W0b + (size_t)(c >> 2) * C_ + k0 + (c & 3) * 8, &sm.st.A[c * 8]);
    }
    const float* xr = xbase + (size_t)(k0 + 2 * kp) * N_;
    float4 q0 = *(const float4*)xr;
    float4 q1 = *(const float4*)(xr + N_);
    float a0[4] = {q0.x, q0.y, q0.z, q0.w};
    float a1[4] = {q1.x, q1.y, q1.z, q1.w};
    uint32* bw = (uint32*)sm.st.Bt;
    #pragma unroll
    for (int i = 0; i < 4; ++i) {
      if (a0[i] > 0.f || a1[i] > 0.f) fl |= (1u << i);
      union { bf16 h[2]; uint32 u; } p;
      p.h[0] = (bf16)a0[i];
      p.h[1] = (bf16)a1[i];
      bw[(n4 + i) * 20 + kp] = p.u;
    }
    __syncthreads();

    bf16x8 af[4], bfr[4];
    #pragma unroll
    for (int mt = 0; mt < 4; ++mt)
      af[mt] = *(const bf16x8*)&sm.st.A[(wave * 64 + mt * 16 + l16) * 32 + l4 * 8];
    #pragma unroll
    for (int nt = 0; nt < 4; ++nt)
      bfr[nt] = *(const bf16x8*)&sm.st.Bt[(nt * 16 + l16) * 40 + l4 * 8];
    #pragma unroll
    for (int mt = 0; mt < 4; ++mt)
      #pragma unroll
      for (int nt = 0; nt < 4; ++nt)
        acc[mt][nt] = __builtin_amdgcn_mfma_f32_16x16x32_bf16(af[mt], bfr[nt], acc[mt][nt], 0, 0, 0);
    __syncthreads();
  }

  #pragma unroll
  for (int i = 0; i < 4; ++i)
    if (fl & (1u << i)) atomicOr(&nflag[n4 + i], 1u);
  __syncthreads();
  if (tid < 64) maskb[(size_t)b * N_ + n0 + tid] = nflag[tid] ? 1.f : 0.f;

  #pragma unroll
  for (int mt = 0; mt < 4; ++mt) {
    int m0 = wave * 64 + mt * 16 + l4 * 4;
    #pragma unroll
    for (int nt = 0; nt < 4; ++nt) {
      int n = nt * 16 + l16;
      bf16x4 hv;
      #pragma unroll
      for (int r = 0; r < 4; ++r) {
        float v = acc[mt][nt][r] + sbias[m0 + r];
        v = fminf(fmaxf(v, 0.f), 1.0e4f);
        hv[r] = (bf16)v;
      }
      *(bf16x4*)&sm.HT[n * 264 + m0] = hv;
    }
  }
  __syncthreads();
  {
    int n = tid >> 2, q = tid & 3;
    const char* src = (const char*)&sm.HT[n * 264 + q * 64];
    bf16* dst = h1T + ((size_t)b * N_ + n0 + n) * H_ + q * 64;
    #pragma unroll
    for (int j = 0; j < 8; ++j)
      *(uint4*)((char*)dst + j * 16) = *(const uint4*)(src + j * 16);
  }
}

// -------------------- fused layers 2+3 -------------------------------------------
// Phase 1: h2[256 x 64n] = clip(relu(W1 h1 + b1)) kept in LDS (HT, stride 264).
// Phase 2: for mb=0..3: y[mb*256.. , 64n] = (W2 h2 + b2) * mask, written via
//          half-tile LDS transpose (YT 128x72) so each thread stores 64B rows.
__global__ __launch_bounds__(256) void gemm23(const bf16* __restrict__ W1b,
                                              const float* __restrict__ b1,
                                              const bf16* __restrict__ W2b,
                                              const float* __restrict__ b2,
                                              const bf16* __restrict__ h1T,
                                              const float* __restrict__ mk,
                                              bf16* __restrict__ yb) {
  __shared__ union {
    struct { bf16 A[256 * 32]; bf16 Bs[64 * 32]; } p1;  // 20480 B (phase-1 staging)
    bf16 A2[256 * 32];                                  // 16384 B (phase-2 staging)
    bf16 YT[128 * 72];                                  // 18432 B (epilogue half-tile)
  } u;
  __shared__ bf16 HT[64 * 264];                         // 33792 B (h2, persistent)
  __shared__ float sb[256];
  __shared__ float smk[64];

  const int tid  = threadIdx.x;
  const int wave = tid >> 6, lane = tid & 63;
  const int l16  = lane & 15, l4 = lane >> 4;
  const int n0   = blockIdx.x * 64;
  const int b    = blockIdx.y;

  sb[tid] = b1[tid];
  if (tid < 64) smk[tid] = mk[(size_t)b * N_ + n0 + tid];

  floatx4 acc[4][4];
  #pragma unroll
  for (int i = 0; i < 4; ++i)
    #pragma unroll
    for (int j = 0; j < 4; ++j)
      acc[i][j] = floatx4{0.f, 0.f, 0.f, 0.f};

  const bf16* Bbase = h1T + ((size_t)b * N_ + n0) * 256;

  // ---------------- phase 1: h2 = clip(relu(W1 h1 + b1)) ----------------
  for (int k0 = 0; k0 < 256; k0 += 32) {
    #pragma unroll
    for (int i = 0; i < 4; ++i) {
      int c = i * 256 + tid;
      gll16(W1b + (size_t)(c >> 2) * 256 + k0 + (c & 3) * 8, &u.p1.A[c * 8]);
    }
    gll16(Bbase + (size_t)(tid >> 2) * 256 + k0 + (tid & 3) * 8, &u.p1.Bs[tid * 8]);
    __syncthreads();

    bf16x8 af[4], bfr[4];
    #pragma unroll
    for (int mt = 0; mt < 4; ++mt)
      af[mt] = *(const bf16x8*)&u.p1.A[(wave * 64 + mt * 16 + l16) * 32 + l4 * 8];
    #pragma unroll
    for (int nt = 0; nt < 4; ++nt)
      bfr[nt] = *(const bf16x8*)&u.p1.Bs[(nt * 16 + l16) * 32 + l4 * 8];
    #pragma unroll
    for (int mt = 0; mt < 4; ++mt)
      #pragma unroll
      for (int nt = 0; nt < 4; ++nt)
        acc[mt][nt] = __builtin_amdgcn_mfma_f32_16x16x32_bf16(af[mt], bfr[nt], acc[mt][nt], 0, 0, 0);
    __syncthreads();
  }

  // h2 -> HT (n-major rows of 256 k, stride 264)
  #pragma unroll
  for (int mt = 0; mt < 4; ++mt) {
    int m0 = wave * 64 + mt * 16 + l4 * 4;
    #pragma unroll
    for (int nt = 0; nt < 4; ++nt) {
      int n = nt * 16 + l16;
      bf16x4 hv;
      #pragma unroll
      for (int r = 0; r < 4; ++r) {
        float v = acc[mt][nt][r] + sb[m0 + r];
        v = fminf(fmaxf(v, 0.f), 1.0e4f);
        hv[r] = (bf16)v;
      }
      *(bf16x4*)&HT[n * 264 + m0] = hv;
    }
  }
  __syncthreads();   // HT complete; also protects sb (b1) until everyone is done

  // ---------------- phase 2: y = (W2 h2 + b2) * mask ----------------
  for (int mb = 0; mb < 4; ++mb) {
    const int m0g = mb * 256;
    { int og = m0g + tid; sb[tid] = (og < O_) ? b2[og] : 0.f; }

    #pragma unroll
    for (int i = 0; i < 4; ++i)
      #pragma unroll
      for (int j = 0; j < 4; ++j)
        acc[i][j] = floatx4{0.f, 0.f, 0.f, 0.f};

    for (int k0 = 0; k0 < 256; k0 += 32) {
      #pragma unroll
      for (int i = 0; i < 4; ++i) {
        int c = i * 256 + tid;
        gll16(W2b + (size_t)(m0g + (c >> 2)) * 256 + k0 + (c & 3) * 8, &u.A2[c * 8]);
      }
      __syncthreads();

      bf16x8 af[4], bfr[4];
      #pragma unroll
      for (int mt = 0; mt < 4; ++mt)
        af[mt] = *(const bf16x8*)&u.A2[(wave * 64 + mt * 16 + l16) * 32 + l4 * 8];
      #pragma unroll
      for (int nt = 0; nt < 4; ++nt)
        bfr[nt] = *(const bf16x8*)&HT[(nt * 16 + l16) * 264 + k0 + l4 * 8];
      #pragma unroll
      for (int mt = 0; mt < 4; ++mt)
        #pragma unroll
        for (int nt = 0; nt < 4; ++nt)
          acc[mt][nt] = __builtin_amdgcn_mfma_f32_16x16x32_bf16(af[mt], bfr[nt], acc[mt][nt], 0, 0, 0);
      __syncthreads();
    }

    // epilogue in 2 half-tiles of 128 o-rows (YT fits union region)
    #pragma unroll
    for (int h = 0; h < 2; ++h) {
      #pragma unroll
      for (int mt = 0; mt < 4; ++mt) {
        int m0 = wave * 64 + mt * 16 + l4 * 4;
        if ((m0 >> 7) == h) {
          #pragma unroll
          for (int nt = 0; nt < 4; ++nt) {
            int n = nt * 16 + l16;
            float m = smk[n];
            #pragma unroll
            for (int r = 0; r < 4; ++r)
              u.YT[(m0 - h * 128 + r) * 72 + n] = (bf16)((acc[mt][nt][r] + sb[m0 + r]) * m);
          }
        }
      }
      __syncthreads();
      {
        int row = tid >> 1, ch = tid & 1;
        const char* src = (const char*)&u.YT[row * 72 + ch * 32];
        bf16* dst = yb + ((size_t)b * OP_ + m0g + h * 128 + row) * N_ + n0 + ch * 32;
        #pragma unroll
        for (int j = 0; j < 4; ++j)
          *(uint4*)((char*)dst + j * 16) = *(const uint4*)(src + j * 16);
      }
      __syncthreads();
    }
  }
}

// -------------------- top-k prefix averaging -------------------------------------
// One wave per (b,o). y is pre-masked. 8000 bf16 -> 4000 u32 words -> monotone u16
// key pairs held in 64 VGPRs (khi = packed pair; lo-half compare derives the shift
// on the fly, saving 64 VGPRs -> higher occupancy). 1-bit radix descent.
__global__ __launch_bounds__(64) void topk(const bf16* __restrict__ y,
                                           const float* __restrict__ maskb,
                                           float* __restrict__ out) {
  __shared__ uint32 cand[128];
  __shared__ float  sval[128];
  __shared__ float  m100[100];
  __shared__ int    gcnt;

  const int lane = threadIdx.x;
  const int o = blockIdx.x, b = blockIdx.y;

  const uint32* yw = (const uint32*)(y + ((size_t)b * OP_ + o) * N_);  // 16000B rows
  const float*  mr = maskb + (size_t)b * N_;

  if (lane == 0) gcnt = 0;
  m100[lane] = mr[lane];
  if (lane < 36) m100[64 + lane] = mr[64 + lane];

  uint32 khi[64];
  #pragma unroll
  for (int i = 0; i < 16; ++i) {
    int base = i * 256 + lane * 4;          // word index; lanes>=40 at i=15 are pad
    bool real = (base < 4000);
    uint4 v = make_uint4(0u, 0u, 0u, 0u);
    if (real) v = *(const uint4*)(yw + base);
    uint32 ww[4] = {v.x, v.y, v.z, v.w};
    #pragma unroll
    for (int j = 0; j < 4; ++j) {
      uint32 w = ww[j];
      uint32 sgn = w & 0x80008000u;
      uint32 mskk = 0x80008000u | (sgn - (sgn >> 15));  // per-half: neg?0xffff:0x8000
      uint32 k = w ^ mskk;                               // packed monotone keys
      if (!real) k = 0u;                                 // pad = strict minimum
      khi[i * 4 + j] = k;
    }
  }

  // 16-sweep 1-bit radix descent for the exact 100th-largest key
  uint32 prefix = 0;
  #pragma unroll 1
  for (int bit = 15; bit >= 0; --bit) {
    uint32 T16 = (prefix | (1u << bit)) << 16;
    int c = 0;
    #pragma unroll
    for (int r = 0; r < 64; ++r) {
      c += (khi[r] >= T16);            // hi-key >= t
      c += ((khi[r] << 16) >= T16);    // lo-key >= t
    }
    #pragma unroll
    for (int m = 1; m < 64; m <<= 1) c += __shfl_xor(c, m, 64);
    if (c >= 100) prefix |= (1u << bit);
  }
  // prefix == T: #{>=T} >= 100, #{>T} <= 99

  // gather strictly-greater keys (<=99), fill ties with T
  #pragma unroll
  for (int r = 0; r < 64; ++r) {
    uint32 h = khi[r] >> 16;
    uint32 l = khi[r] & 0xffffu;
    if (h > prefix) { int p = atomicAdd(&gcnt, 1); cand[p] = h; }
    if (l > prefix) { int p = atomicAdd(&gcnt, 1); cand[p] = l; }
  }
  __syncthreads();
  int cg = gcnt;
  for (int idx = lane; idx < 100; idx += 64)
    if (idx >= cg) cand[idx] = prefix;
  __syncthreads();

  // rank-sort 100 keys (broadcast LDS reads), convert key -> fp32 value
  for (int idx = lane; idx < 100; idx += 64) {
    uint32 ci = cand[idx];
    int rank = 0;
    for (int j = 0; j < 100; ++j) {
      uint32 cj = cand[j];
      rank += (cj > ci) || (cj == ci && j < idx);
    }
    uint32 bb = (ci & 0x8000u) ? (ci & 0x7fffu) : (~ci & 0xffffu);
    sval[rank] = __uint_as_float(bb << 16);
  }
  __syncthreads();

  if (lane == 0) {
    const int KSv[4] = {10, 25, 50, 100};
    float num = 0.f, den = 0.f, pred = 0.f;
    int ki = 0;
    for (int j = 0; j < 100; ++j) {
      num += sval[j] * m100[j];
      den += m100[j];
      if (j + 1 == KSv[ki]) { pred += 0.25f * num / den; ++ki; }
    }
    out[(size_t)b * O_ + o] = pred;
  }
}

// -------------------- launcher ---------------------------------------------------
extern "C" void kernel_launch(void* const* d_in, const int* in_sizes, int n_in,
                              void* d_out, int out_size, void* d_ws, size_t ws_size,
                              hipStream_t stream) {
  const float* x  = (const float*)d_in[0];
  const float* W0 = (const float*)d_in[1];
  const float* b0 = (const float*)d_in[2];
  const float* W1 = (const float*)d_in[3];
  const float* b1 = (const float*)d_in[4];
  const float* W2 = (const float*)d_in[5];
  const float* b2 = (const float*)d_in[6];
  float* out = (float*)d_out;

  char* ws = (char*)d_ws;
  bf16*  W0b  = (bf16*)(ws + 0);          // 1,048,576 B
  bf16*  W1b  = (bf16*)(ws + 1048576);    //   131,072 B
  bf16*  W2b  = (bf16*)(ws + 1179648);    //   524,288 B
  float* mk   = (float*)(ws + 1703936);   //   256,000 B
  bf16*  h1T  = (bf16*)(ws + 1959936);    // 32,768,000 B
  bf16*  yb   = (bf16*)(ws + 34727936);   // 131,072,000 B

  castw<<<832, 256, 0, stream>>>(W0, W1, W2, W0b, W1b, W2b);
  gemm1<<<dim3(125, 8), 256, 0, stream>>>(x, W0b, b0, h1T, mk);
  gemm23<<<dim3(125, 8), 256, 0, stream>>>(W1b, b1, W2b, b2, h1T, mk, yb);
  topk<<<dim3(1000, 8), 64, 0, stream>>>(yb, mk, out);
}

// Round 2
// 922.953 us; speedup vs baseline: 1.0689x; 1.0549x over previous
//
#include <hip/hip_runtime.h>
#include <hip/hip_bf16.h>
#include <stdint.h>

typedef __bf16 bf16;
typedef __bf16 bf16x8 __attribute__((ext_vector_type(8)));
typedef __bf16 bf16x4 __attribute__((ext_vector_type(4)));
typedef float  floatx4 __attribute__((ext_vector_type(4)));
typedef unsigned int uint32;

#define B_  8
#define C_  2048
#define N_  8000
#define H_  256
#define O_  1000
#define OP_ 1024   // O padded to MFMA-friendly 1024

// async global->LDS, 16B per lane; LDS dst = wave-uniform base + lane*16
__device__ __forceinline__ void gll16(const void* g, void* l) {
  __builtin_amdgcn_global_load_lds((const __attribute__((address_space(1))) void*)g,
                                   (__attribute__((address_space(3))) void*)l, 16, 0, 0);
}

// -------------------- weight pre-cast (fp32 -> bf16, W2 padded to 1024 rows) -----
// vectorized: one float4 -> bf16x4 per thread. 212992 groups = 832 blocks exactly.
__global__ __launch_bounds__(256) void castw(const float* __restrict__ W0,
                                             const float* __restrict__ W1,
                                             const float* __restrict__ W2,
                                             bf16* __restrict__ W0b,
                                             bf16* __restrict__ W1b,
                                             bf16* __restrict__ W2b) {
  int g = blockIdx.x * 256 + threadIdx.x;     // < 212992
  float4 v;
  bf16* dst;
  if (g < 131072) {                           // W0: 524288 elems
    v = ((const float4*)W0)[g];
    dst = W0b + g * 4;
  } else if (g < 147456) {                    // W1: 65536 elems
    int i = g - 131072;
    v = ((const float4*)W1)[i];
    dst = W1b + i * 4;
  } else {                                    // W2 padded: 262144 elems
    int i = g - 147456;
    int o = i >> 6, k4 = i & 63;
    if (o < O_) v = *(const float4*)(W2 + o * 256 + k4 * 4);
    else        v = make_float4(0.f, 0.f, 0.f, 0.f);
    dst = W2b + i * 4;
  }
  bf16x4 r;
  r[0] = (bf16)v.x; r[1] = (bf16)v.y; r[2] = (bf16)v.z; r[3] = (bf16)v.w;
  *(bf16x4*)dst = r;
}

// -------------------- fused layers 1+2+3 -----------------------------------------
// Phase A: h1 = clip(relu(W0 x + b0))      -> HT (LDS, [64 n][264 stride])
// Phase B: h2 = clip(relu(W1 h1 + b1))     -> HT (overwrite after full consumption)
// Phase C: for mb=0..3: y = (W2 h2 + b2)*mask -> yb (half-tile LDS transpose)
// h1/h2 never touch HBM. Mask derived in-block (nflag) and also stored for topk.
__global__ __launch_bounds__(256) void gemm123(const float* __restrict__ x,
                                               const bf16* __restrict__ W0b,
                                               const float* __restrict__ b0,
                                               const bf16* __restrict__ W1b,
                                               const float* __restrict__ b1,
                                               const bf16* __restrict__ W2b,
                                               const float* __restrict__ b2,
                                               float* __restrict__ maskb,
                                               bf16* __restrict__ yb) {
  __shared__ union {
    struct { bf16 A[256 * 32]; bf16 Bt[64 * 40]; } st;  // 21504 B staging
    bf16 YT[128 * 72];                                  // 18432 B epilogue half-tile
  } u;
  __shared__ bf16 HT[64 * 264];                         // 33792 B persistent h1/h2
  __shared__ float sb[256];
  __shared__ float smk[64];
  __shared__ uint32 nflag[64];

  const int tid  = threadIdx.x;
  const int wave = tid >> 6, lane = tid & 63;
  const int l16  = lane & 15, l4 = lane >> 4;
  const int n0   = blockIdx.x * 64;
  const int b    = blockIdx.y;

  sb[tid] = b0[tid];
  if (tid < 64) nflag[tid] = 0;

  const int kp = tid >> 4;          // 0..15 -> k-pair 2*kp
  const int n4 = (tid & 15) * 4;    // 0..60
  const float* xbase = x + (size_t)b * C_ * N_ + n0 + n4;

  floatx4 acc[4][4];
  #pragma unroll
  for (int i = 0; i < 4; ++i)
    #pragma unroll
    for (int j = 0; j < 4; ++j)
      acc[i][j] = floatx4{0.f, 0.f, 0.f, 0.f};

  uint32 fl = 0;

  // ---------------- phase A: h1 = clip(relu(W0 x + b0)) ----------------
  for (int k0 = 0; k0 < C_; k0 += 32) {
    #pragma unroll
    for (int i = 0; i < 4; ++i) {
      int c = i * 256 + tid;
      gll16(W0b + (size_t)(c >> 2) * C_ + k0 + (c & 3) * 8, &u.st.A[c * 8]);
    }
    const float* xr = xbase + (size_t)(k0 + 2 * kp) * N_;
    float4 q0 = *(const float4*)xr;
    float4 q1 = *(const float4*)(xr + N_);
    float a0[4] = {q0.x, q0.y, q0.z, q0.w};
    float a1[4] = {q1.x, q1.y, q1.z, q1.w};
    uint32* bw = (uint32*)u.st.Bt;
    #pragma unroll
    for (int i = 0; i < 4; ++i) {
      if (a0[i] > 0.f || a1[i] > 0.f) fl |= (1u << i);
      union { bf16 h[2]; uint32 u32v; } p;
      p.h[0] = (bf16)a0[i];
      p.h[1] = (bf16)a1[i];
      bw[(n4 + i) * 20 + kp] = p.u32v;
    }
    __syncthreads();

    bf16x8 af[4], bfr[4];
    #pragma unroll
    for (int mt = 0; mt < 4; ++mt)
      af[mt] = *(const bf16x8*)&u.st.A[(wave * 64 + mt * 16 + l16) * 32 + l4 * 8];
    #pragma unroll
    for (int nt = 0; nt < 4; ++nt)
      bfr[nt] = *(const bf16x8*)&u.st.Bt[(nt * 16 + l16) * 40 + l4 * 8];
    #pragma unroll
    for (int mt = 0; mt < 4; ++mt)
      #pragma unroll
      for (int nt = 0; nt < 4; ++nt)
        acc[mt][nt] = __builtin_amdgcn_mfma_f32_16x16x32_bf16(af[mt], bfr[nt], acc[mt][nt], 0, 0, 0);
    __syncthreads();
  }

  // mask: tile real iff any feature > 0 (column of x)
  #pragma unroll
  for (int i = 0; i < 4; ++i)
    if (fl & (1u << i)) atomicOr(&nflag[n4 + i], 1u);
  __syncthreads();
  if (tid < 64) {
    float m = nflag[tid] ? 1.f : 0.f;
    smk[tid] = m;
    maskb[(size_t)b * N_ + n0 + tid] = m;
  }

  // h1 -> HT
  #pragma unroll
  for (int mt = 0; mt < 4; ++mt) {
    int m0 = wave * 64 + mt * 16 + l4 * 4;
    #pragma unroll
    for (int nt = 0; nt < 4; ++nt) {
      int n = nt * 16 + l16;
      bf16x4 hv;
      #pragma unroll
      for (int r = 0; r < 4; ++r) {
        float v = acc[mt][nt][r] + sb[m0 + r];
        v = fminf(fmaxf(v, 0.f), 1.0e4f);
        hv[r] = (bf16)v;
      }
      *(bf16x4*)&HT[n * 264 + m0] = hv;
    }
  }
  __syncthreads();   // HT(h1) complete; sb(b0) fully consumed

  // ---------------- phase B: h2 = clip(relu(W1 h1 + b1)) ----------------
  sb[tid] = b1[tid];
  #pragma unroll
  for (int i = 0; i < 4; ++i)
    #pragma unroll
    for (int j = 0; j < 4; ++j)
      acc[i][j] = floatx4{0.f, 0.f, 0.f, 0.f};

  for (int k0 = 0; k0 < 256; k0 += 32) {
    #pragma unroll
    for (int i = 0; i < 4; ++i) {
      int c = i * 256 + tid;
      gll16(W1b + (size_t)(c >> 2) * 256 + k0 + (c & 3) * 8, &u.st.A[c * 8]);
    }
    __syncthreads();

    bf16x8 af[4], bfr[4];
    #pragma unroll
    for (int mt = 0; mt < 4; ++mt)
      af[mt] = *(const bf16x8*)&u.st.A[(wave * 64 + mt * 16 + l16) * 32 + l4 * 8];
    #pragma unroll
    for (int nt = 0; nt < 4; ++nt)
      bfr[nt] = *(const bf16x8*)&HT[(nt * 16 + l16) * 264 + k0 + l4 * 8];  // B direct from LDS
    #pragma unroll
    for (int mt = 0; mt < 4; ++mt)
      #pragma unroll
      for (int nt = 0; nt < 4; ++nt)
        acc[mt][nt] = __builtin_amdgcn_mfma_f32_16x16x32_bf16(af[mt], bfr[nt], acc[mt][nt], 0, 0, 0);
    __syncthreads();   // final sync: all waves done reading HT(h1)
  }

  // h2 -> HT (overwrite)
  #pragma unroll
  for (int mt = 0; mt < 4; ++mt) {
    int m0 = wave * 64 + mt * 16 + l4 * 4;
    #pragma unroll
    for (int nt = 0; nt < 4; ++nt) {
      int n = nt * 16 + l16;
      bf16x4 hv;
      #pragma unroll
      for (int r = 0; r < 4; ++r) {
        float v = acc[mt][nt][r] + sb[m0 + r];
        v = fminf(fmaxf(v, 0.f), 1.0e4f);
        hv[r] = (bf16)v;
      }
      *(bf16x4*)&HT[n * 264 + m0] = hv;
    }
  }
  __syncthreads();   // HT(h2) complete; sb(b1) fully consumed

  // ---------------- phase C: y = (W2 h2 + b2) * mask ----------------
  for (int mb = 0; mb < 4; ++mb) {
    const int m0g = mb * 256;
    { int og = m0g + tid; sb[tid] = (og < O_) ? b2[og] : 0.f; }

    #pragma unroll
    for (int i = 0; i < 4; ++i)
      #pragma unroll
      for (int j = 0; j < 4; ++j)
        acc[i][j] = floatx4{0.f, 0.f, 0.f, 0.f};

    for (int k0 = 0; k0 < 256; k0 += 32) {
      #pragma unroll
      for (int i = 0; i < 4; ++i) {
        int c = i * 256 + tid;
        gll16(W2b + (size_t)(m0g + (c >> 2)) * 256 + k0 + (c & 3) * 8, &u.st.A[c * 8]);
      }
      __syncthreads();

      bf16x8 af[4], bfr[4];
      #pragma unroll
      for (int mt = 0; mt < 4; ++mt)
        af[mt] = *(const bf16x8*)&u.st.A[(wave * 64 + mt * 16 + l16) * 32 + l4 * 8];
      #pragma unroll
      for (int nt = 0; nt < 4; ++nt)
        bfr[nt] = *(const bf16x8*)&HT[(nt * 16 + l16) * 264 + k0 + l4 * 8];
      #pragma unroll
      for (int mt = 0; mt < 4; ++mt)
        #pragma unroll
        for (int nt = 0; nt < 4; ++nt)
          acc[mt][nt] = __builtin_amdgcn_mfma_f32_16x16x32_bf16(af[mt], bfr[nt], acc[mt][nt], 0, 0, 0);
      __syncthreads();
    }

    // epilogue in 2 half-tiles of 128 o-rows (YT overlays staging region)
    #pragma unroll
    for (int h = 0; h < 2; ++h) {
      #pragma unroll
      for (int mt = 0; mt < 4; ++mt) {
        int m0 = wave * 64 + mt * 16 + l4 * 4;
        if ((m0 >> 7) == h) {
          #pragma unroll
          for (int nt = 0; nt < 4; ++nt) {
            int n = nt * 16 + l16;
            float m = smk[n];
            #pragma unroll
            for (int r = 0; r < 4; ++r)
              u.YT[(m0 - h * 128 + r) * 72 + n] = (bf16)((acc[mt][nt][r] + sb[m0 + r]) * m);
          }
        }
      }
      __syncthreads();
      {
        int row = tid >> 1, ch = tid & 1;
        int og = m0g + h * 128 + row;
        if (og < O_) {   // padded o-rows never read by topk
          const char* src = (const char*)&u.YT[row * 72 + ch * 32];
          bf16* dst = yb + ((size_t)b * OP_ + og) * N_ + n0 + ch * 32;
          #pragma unroll
          for (int j = 0; j < 4; ++j)
            *(uint4*)((char*)dst + j * 16) = *(const uint4*)(src + j * 16);
        }
      }
      __syncthreads();
    }
  }
}

// -------------------- top-k prefix averaging -------------------------------------
// One wave per (b,o). y is pre-masked. 8000 bf16 -> 4000 u32 words -> monotone u16
// key pairs held in 64 VGPRs (khi = packed pair; lo-half compare derives the shift
// on the fly). 1-bit radix descent; single wave => no barriers in the hot part.
__global__ __launch_bounds__(64) void topk(const bf16* __restrict__ y,
                                           const float* __restrict__ maskb,
                                           float* __restrict__ out) {
  __shared__ uint32 cand[128];
  __shared__ float  sval[128];
  __shared__ float  m100[100];
  __shared__ int    gcnt;

  const int lane = threadIdx.x;
  const int o = blockIdx.x, b = blockIdx.y;

  const uint32* yw = (const uint32*)(y + ((size_t)b * OP_ + o) * N_);  // 16000B rows
  const float*  mr = maskb + (size_t)b * N_;

  if (lane == 0) gcnt = 0;
  m100[lane] = mr[lane];
  if (lane < 36) m100[64 + lane] = mr[64 + lane];

  uint32 khi[64];
  #pragma unroll
  for (int i = 0; i < 16; ++i) {
    int base = i * 256 + lane * 4;          // word index; lanes>=40 at i=15 are pad
    bool real = (base < 4000);
    uint4 v = make_uint4(0u, 0u, 0u, 0u);
    if (real) v = *(const uint4*)(yw + base);
    uint32 ww[4] = {v.x, v.y, v.z, v.w};
    #pragma unroll
    for (int j = 0; j < 4; ++j) {
      uint32 w = ww[j];
      uint32 sgn = w & 0x80008000u;
      uint32 mskk = 0x80008000u | (sgn - (sgn >> 15));  // per-half: neg?0xffff:0x8000
      uint32 k = w ^ mskk;                               // packed monotone keys
      if (!real) k = 0u;                                 // pad = strict minimum
      khi[i * 4 + j] = k;
    }
  }

  // 16-sweep 1-bit radix descent for the exact 100th-largest key
  uint32 prefix = 0;
  #pragma unroll 1
  for (int bit = 15; bit >= 0; --bit) {
    uint32 T16 = (prefix | (1u << bit)) << 16;
    int c = 0;
    #pragma unroll
    for (int r = 0; r < 64; ++r) {
      c += (khi[r] >= T16);            // hi-key >= t
      c += ((khi[r] << 16) >= T16);    // lo-key >= t
    }
    #pragma unroll
    for (int m = 1; m < 64; m <<= 1) c += __shfl_xor(c, m, 64);
    if (c >= 100) prefix |= (1u << bit);
  }
  // prefix == T: #{>=T} >= 100, #{>T} <= 99

  // gather strictly-greater keys (<=99), fill ties with T
  #pragma unroll
  for (int r = 0; r < 64; ++r) {
    uint32 h = khi[r] >> 16;
    uint32 l = khi[r] & 0xffffu;
    if (h > prefix) { int p = atomicAdd(&gcnt, 1); cand[p] = h; }
    if (l > prefix) { int p = atomicAdd(&gcnt, 1); cand[p] = l; }
  }
  __syncthreads();
  int cg = gcnt;
  for (int idx = lane; idx < 100; idx += 64)
    if (idx >= cg) cand[idx] = prefix;
  __syncthreads();

  // rank-sort 100 keys (broadcast LDS reads), convert key -> fp32 value
  for (int idx = lane; idx < 100; idx += 64) {
    uint32 ci = cand[idx];
    int rank = 0;
    for (int j = 0; j < 100; ++j) {
      uint32 cj = cand[j];
      rank += (cj > ci) || (cj == ci && j < idx);
    }
    uint32 bb = (ci & 0x8000u) ? (ci & 0x7fffu) : (~ci & 0xffffu);
    sval[rank] = __uint_as_float(bb << 16);
  }
  __syncthreads();

  if (lane == 0) {
    const int KSv[4] = {10, 25, 50, 100};
    float num = 0.f, den = 0.f, pred = 0.f;
    int ki = 0;
    for (int j = 0; j < 100; ++j) {
      num += sval[j] * m100[j];
      den += m100[j];
      if (j + 1 == KSv[ki]) { pred += 0.25f * num / den; ++ki; }
    }
    out[(size_t)b * O_ + o] = pred;
  }
}

// -------------------- launcher ---------------------------------------------------
extern "C" void kernel_launch(void* const* d_in, const int* in_sizes, int n_in,
                              void* d_out, int out_size, void* d_ws, size_t ws_size,
                              hipStream_t stream) {
  const float* x  = (const float*)d_in[0];
  const float* W0 = (const float*)d_in[1];
  const float* b0 = (const float*)d_in[2];
  const float* W1 = (const float*)d_in[3];
  const float* b1 = (const float*)d_in[4];
  const float* W2 = (const float*)d_in[5];
  const float* b2 = (const float*)d_in[6];
  float* out = (float*)d_out;

  char* ws = (char*)d_ws;
  bf16*  W0b  = (bf16*)(ws + 0);          // 1,048,576 B
  bf16*  W1b  = (bf16*)(ws + 1048576);    //   131,072 B
  bf16*  W2b  = (bf16*)(ws + 1179648);    //   524,288 B
  float* mk   = (float*)(ws + 1703936);   //   256,000 B
  bf16*  yb   = (bf16*)(ws + 1959936);    // 131,072,000 B

  castw<<<832, 256, 0, stream>>>(W0, W1, W2, W0b, W1b, W2b);
  gemm123<<<dim3(125, 8), 256, 0, stream>>>(x, W0b, b0, W1b, b1, W2b, b2, mk, yb);
  topk<<<dim3(1000, 8), 64, 0, stream>>>(yb, mk, out);
}

// Round 3
// 916.153 us; speedup vs baseline: 1.0769x; 1.0074x over previous
//
#include <hip/hip_runtime.h>
#include <hip/hip_bf16.h>
#include <stdint.h>

typedef __bf16 bf16;
typedef __bf16 bf16x8 __attribute__((ext_vector_type(8)));
typedef __bf16 bf16x4 __attribute__((ext_vector_type(4)));
typedef float  floatx4 __attribute__((ext_vector_type(4)));
typedef unsigned int uint32;

#define B_  8
#define C_  2048
#define N_  8000
#define H_  256
#define O_  1000
#define OP_ 1024   // O padded to MFMA-friendly 1024

// async global->LDS, 16B per lane; LDS dst = wave-uniform base + lane*16
__device__ __forceinline__ void gll16(const void* g, void* l) {
  __builtin_amdgcn_global_load_lds((const __attribute__((address_space(1))) void*)g,
                                   (__attribute__((address_space(3))) void*)l, 16, 0, 0);
}
// raw pipeline primitives (T3-minimum): counted drains + raw barrier.
__device__ __forceinline__ void wait_vm0()   { asm volatile("s_waitcnt vmcnt(0)" ::: "memory"); }
__device__ __forceinline__ void wait_lgkm0() { asm volatile("s_waitcnt lgkmcnt(0)" ::: "memory"); }
__device__ __forceinline__ void bar_raw()    { __builtin_amdgcn_s_barrier(); }

// -------------------- weight pre-cast (fp32 -> bf16, W2 padded to 1024 rows) -----
__global__ __launch_bounds__(256) void castw(const float* __restrict__ W0,
                                             const float* __restrict__ W1,
                                             const float* __restrict__ W2,
                                             bf16* __restrict__ W0b,
                                             bf16* __restrict__ W1b,
                                             bf16* __restrict__ W2b) {
  int g = blockIdx.x * 256 + threadIdx.x;     // < 212992
  float4 v;
  bf16* dst;
  if (g < 131072) {                           // W0: 524288 elems
    v = ((const float4*)W0)[g];
    dst = W0b + g * 4;
  } else if (g < 147456) {                    // W1: 65536 elems
    int i = g - 131072;
    v = ((const float4*)W1)[i];
    dst = W1b + i * 4;
  } else {                                    // W2 padded: 262144 elems
    int i = g - 147456;
    int o = i >> 6, k4 = i & 63;
    if (o < O_) v = *(const float4*)(W2 + o * 256 + k4 * 4);
    else        v = make_float4(0.f, 0.f, 0.f, 0.f);
    dst = W2b + i * 4;
  }
  bf16x4 r;
  r[0] = (bf16)v.x; r[1] = (bf16)v.y; r[2] = (bf16)v.z; r[3] = (bf16)v.w;
  *(bf16x4*)dst = r;
}

// -------------------- fused layers 1+2+3, single-barrier pipelined ---------------
// Phase A: h1 = clip(relu(W0 x + b0))      -> HT   (x + W0 double-buffered)
// Phase B: h2 = clip(relu(W1 h1 + b1))     -> HT   (W1 double-buffered)
// Phase C: y  = (W2 h2 + b2) * mask        -> yb   (W2 double-buffered, mb=0..3)
// One raw s_barrier per K-step; prefetch issued POST-barrier stays in flight
// across the MFMA phase (safe: a wave at barrier(k) has finished MFMA(k-1)
// reads in program order, so the k-1 buffer is free for tile k+1).
__global__ __launch_bounds__(256) void gemm123(const float* __restrict__ x,
                                               const bf16* __restrict__ W0b,
                                               const float* __restrict__ b0,
                                               const bf16* __restrict__ W1b,
                                               const float* __restrict__ b1,
                                               const bf16* __restrict__ W2b,
                                               const float* __restrict__ b2,
                                               float* __restrict__ maskb,
                                               bf16* __restrict__ yb) {
  __shared__ union {
    struct { bf16 A[2][256 * 32]; bf16 Bt[2][64 * 40]; } st;  // 43008 B dbuf staging
    bf16 YT[128 * 72];                                        // 18432 B epilogue
  } u;
  __shared__ bf16 HT[64 * 264];                               // 33792 B persistent
  __shared__ float sb[256];
  __shared__ float smk[64];
  __shared__ uint32 nflag[64];

  const int tid  = threadIdx.x;
  const int wave = tid >> 6, lane = tid & 63;
  const int l16  = lane & 15, l4 = lane >> 4;
  const int n0   = blockIdx.x * 64;
  const int b    = blockIdx.y;

  sb[tid] = b0[tid];
  if (tid < 64) nflag[tid] = 0;

  const int kp = tid >> 4;          // 0..15 -> k-pair 2*kp
  const int n4 = (tid & 15) * 4;    // 0..60
  const float* xbase = x + (size_t)b * C_ * N_ + n0 + n4;

  floatx4 acc[4][4];
  #pragma unroll
  for (int i = 0; i < 4; ++i)
    #pragma unroll
    for (int j = 0; j < 4; ++j)
      acc[i][j] = floatx4{0.f, 0.f, 0.f, 0.f};

  uint32 fl = 0;

  // ---------------- phase A ----------------
  // prologue: stage tile 0
  #pragma unroll
  for (int i = 0; i < 4; ++i) {
    int c = i * 256 + tid;
    gll16(W0b + (size_t)(c >> 2) * C_ + (c & 3) * 8, &u.st.A[0][c * 8]);
  }
  float4 q0 = *(const float4*)(xbase + (size_t)(2 * kp) * N_);
  float4 q1 = *(const float4*)(xbase + (size_t)(2 * kp + 1) * N_);

  for (int k0 = 0; k0 < C_; k0 += 32) {
    const int cur = (k0 >> 5) & 1, nxt = cur ^ 1;
    wait_vm0();                       // tile k (W0 gll16 + x regs) arrived
    {
      float a0[4] = {q0.x, q0.y, q0.z, q0.w};
      float a1[4] = {q1.x, q1.y, q1.z, q1.w};
      uint32* bw = (uint32*)u.st.Bt[cur];
      #pragma unroll
      for (int i = 0; i < 4; ++i) {
        if (a0[i] > 0.f || a1[i] > 0.f) fl |= (1u << i);
        union { bf16 h[2]; uint32 u32v; } p;
        p.h[0] = (bf16)a0[i];
        p.h[1] = (bf16)a1[i];
        bw[(n4 + i) * 20 + kp] = p.u32v;
      }
    }
    wait_lgkm0();                     // Bt(cur) writes complete
    bar_raw();                        // tile k visible; prev buffer free
    if (k0 + 32 < C_) {               // prefetch tile k+1 (in flight across MFMA)
      #pragma unroll
      for (int i = 0; i < 4; ++i) {
        int c = i * 256 + tid;
        gll16(W0b + (size_t)(c >> 2) * C_ + (k0 + 32) + (c & 3) * 8, &u.st.A[nxt][c * 8]);
      }
      const float* xr = xbase + (size_t)(k0 + 32 + 2 * kp) * N_;
      q0 = *(const float4*)xr;
      q1 = *(const float4*)(xr + N_);
    }
    bf16x8 af[4], bfr[4];
    #pragma unroll
    for (int mt = 0; mt < 4; ++mt)
      af[mt] = *(const bf16x8*)&u.st.A[cur][(wave * 64 + mt * 16 + l16) * 32 + l4 * 8];
    #pragma unroll
    for (int nt = 0; nt < 4; ++nt)
      bfr[nt] = *(const bf16x8*)&u.st.Bt[cur][(nt * 16 + l16) * 40 + l4 * 8];
    #pragma unroll
    for (int mt = 0; mt < 4; ++mt)
      #pragma unroll
      for (int nt = 0; nt < 4; ++nt)
        acc[mt][nt] = __builtin_amdgcn_mfma_f32_16x16x32_bf16(af[mt], bfr[nt], acc[mt][nt], 0, 0, 0);
  }

  // mask: tile real iff any feature > 0 (column of x)
  #pragma unroll
  for (int i = 0; i < 4; ++i)
    if (fl & (1u << i)) atomicOr(&nflag[n4 + i], 1u);
  __syncthreads();
  if (tid < 64) {
    float m = nflag[tid] ? 1.f : 0.f;
    smk[tid] = m;
    maskb[(size_t)b * N_ + n0 + tid] = m;
  }

  // h1 -> HT
  #pragma unroll
  for (int mt = 0; mt < 4; ++mt) {
    int m0 = wave * 64 + mt * 16 + l4 * 4;
    #pragma unroll
    for (int nt = 0; nt < 4; ++nt) {
      int n = nt * 16 + l16;
      bf16x4 hv;
      #pragma unroll
      for (int r = 0; r < 4; ++r) {
        float v = acc[mt][nt][r] + sb[m0 + r];
        v = fminf(fmaxf(v, 0.f), 1.0e4f);
        hv[r] = (bf16)v;
      }
      *(bf16x4*)&HT[n * 264 + m0] = hv;
    }
  }
  __syncthreads();   // HT(h1) complete; sb(b0) fully consumed

  // ---------------- phase B ----------------
  sb[tid] = b1[tid];
  #pragma unroll
  for (int i = 0; i < 4; ++i)
    #pragma unroll
    for (int j = 0; j < 4; ++j)
      acc[i][j] = floatx4{0.f, 0.f, 0.f, 0.f};

  #pragma unroll
  for (int i = 0; i < 4; ++i) {      // prologue tile 0
    int c = i * 256 + tid;
    gll16(W1b + (size_t)(c >> 2) * 256 + (c & 3) * 8, &u.st.A[0][c * 8]);
  }
  for (int k0 = 0; k0 < 256; k0 += 32) {
    const int cur = (k0 >> 5) & 1, nxt = cur ^ 1;
    wait_vm0();
    bar_raw();
    if (k0 + 32 < 256) {
      #pragma unroll
      for (int i = 0; i < 4; ++i) {
        int c = i * 256 + tid;
        gll16(W1b + (size_t)(c >> 2) * 256 + (k0 + 32) + (c & 3) * 8, &u.st.A[nxt][c * 8]);
      }
    }
    bf16x8 af[4], bfr[4];
    #pragma unroll
    for (int mt = 0; mt < 4; ++mt)
      af[mt] = *(const bf16x8*)&u.st.A[cur][(wave * 64 + mt * 16 + l16) * 32 + l4 * 8];
    #pragma unroll
    for (int nt = 0; nt < 4; ++nt)
      bfr[nt] = *(const bf16x8*)&HT[(nt * 16 + l16) * 264 + k0 + l4 * 8];
    #pragma unroll
    for (int mt = 0; mt < 4; ++mt)
      #pragma unroll
      for (int nt = 0; nt < 4; ++nt)
        acc[mt][nt] = __builtin_amdgcn_mfma_f32_16x16x32_bf16(af[mt], bfr[nt], acc[mt][nt], 0, 0, 0);
  }
  __syncthreads();   // all waves done reading HT(h1)

  // h2 -> HT (overwrite)
  #pragma unroll
  for (int mt = 0; mt < 4; ++mt) {
    int m0 = wave * 64 + mt * 16 + l4 * 4;
    #pragma unroll
    for (int nt = 0; nt < 4; ++nt) {
      int n = nt * 16 + l16;
      bf16x4 hv;
      #pragma unroll
      for (int r = 0; r < 4; ++r) {
        float v = acc[mt][nt][r] + sb[m0 + r];
        v = fminf(fmaxf(v, 0.f), 1.0e4f);
        hv[r] = (bf16)v;
      }
      *(bf16x4*)&HT[n * 264 + m0] = hv;
    }
  }
  __syncthreads();   // HT(h2) complete

  // ---------------- phase C ----------------
  for (int mb = 0; mb < 4; ++mb) {
    const int m0g = mb * 256;
    { int og = m0g + tid; sb[tid] = (og < O_) ? b2[og] : 0.f; }

    #pragma unroll
    for (int i = 0; i < 4; ++i)
      #pragma unroll
      for (int j = 0; j < 4; ++j)
        acc[i][j] = floatx4{0.f, 0.f, 0.f, 0.f};

    #pragma unroll
    for (int i = 0; i < 4; ++i) {    // prologue tile 0
      int c = i * 256 + tid;
      gll16(W2b + (size_t)(m0g + (c >> 2)) * 256 + (c & 3) * 8, &u.st.A[0][c * 8]);
    }
    for (int k0 = 0; k0 < 256; k0 += 32) {
      const int cur = (k0 >> 5) & 1, nxt = cur ^ 1;
      wait_vm0();
      bar_raw();
      if (k0 + 32 < 256) {
        #pragma unroll
        for (int i = 0; i < 4; ++i) {
          int c = i * 256 + tid;
          gll16(W2b + (size_t)(m0g + (c >> 2)) * 256 + (k0 + 32) + (c & 3) * 8, &u.st.A[nxt][c * 8]);
        }
      }
      bf16x8 af[4], bfr[4];
      #pragma unroll
      for (int mt = 0; mt < 4; ++mt)
        af[mt] = *(const bf16x8*)&u.st.A[cur][(wave * 64 + mt * 16 + l16) * 32 + l4 * 8];
      #pragma unroll
      for (int nt = 0; nt < 4; ++nt)
        bfr[nt] = *(const bf16x8*)&HT[(nt * 16 + l16) * 264 + k0 + l4 * 8];
      #pragma unroll
      for (int mt = 0; mt < 4; ++mt)
        #pragma unroll
        for (int nt = 0; nt < 4; ++nt)
          acc[mt][nt] = __builtin_amdgcn_mfma_f32_16x16x32_bf16(af[mt], bfr[nt], acc[mt][nt], 0, 0, 0);
    }
    __syncthreads();   // staging region free -> safe for YT overlay

    // epilogue in 2 half-tiles of 128 o-rows (YT overlays staging region)
    #pragma unroll
    for (int h = 0; h < 2; ++h) {
      #pragma unroll
      for (int mt = 0; mt < 4; ++mt) {
        int m0 = wave * 64 + mt * 16 + l4 * 4;
        if ((m0 >> 7) == h) {
          #pragma unroll
          for (int nt = 0; nt < 4; ++nt) {
            int n = nt * 16 + l16;
            float m = smk[n];
            #pragma unroll
            for (int r = 0; r < 4; ++r)
              u.YT[(m0 - h * 128 + r) * 72 + n] = (bf16)((acc[mt][nt][r] + sb[m0 + r]) * m);
          }
        }
      }
      __syncthreads();
      {
        int row = tid >> 1, ch = tid & 1;
        int og = m0g + h * 128 + row;
        if (og < O_) {   // padded o-rows never read by topk
          const char* src = (const char*)&u.YT[row * 72 + ch * 32];
          bf16* dst = yb + ((size_t)b * OP_ + og) * N_ + n0 + ch * 32;
          #pragma unroll
          for (int j = 0; j < 4; ++j)
            *(uint4*)((char*)dst + j * 16) = *(const uint4*)(src + j * 16);
        }
      }
      __syncthreads();
    }
  }
}

// -------------------- top-k prefix averaging -------------------------------------
__global__ __launch_bounds__(64) void topk(const bf16* __restrict__ y,
                                           const float* __restrict__ maskb,
                                           float* __restrict__ out) {
  __shared__ uint32 cand[128];
  __shared__ float  sval[128];
  __shared__ float  m100[100];
  __shared__ int    gcnt;

  const int lane = threadIdx.x;
  const int o = blockIdx.x, b = blockIdx.y;

  const uint32* yw = (const uint32*)(y + ((size_t)b * OP_ + o) * N_);  // 16000B rows
  const float*  mr = maskb + (size_t)b * N_;

  if (lane == 0) gcnt = 0;
  m100[lane] = mr[lane];
  if (lane < 36) m100[64 + lane] = mr[64 + lane];

  uint32 khi[64];
  #pragma unroll
  for (int i = 0; i < 16; ++i) {
    int base = i * 256 + lane * 4;          // word index; lanes>=40 at i=15 are pad
    bool real = (base < 4000);
    uint4 v = make_uint4(0u, 0u, 0u, 0u);
    if (real) v = *(const uint4*)(yw + base);
    uint32 ww[4] = {v.x, v.y, v.z, v.w};
    #pragma unroll
    for (int j = 0; j < 4; ++j) {
      uint32 w = ww[j];
      uint32 sgn = w & 0x80008000u;
      uint32 mskk = 0x80008000u | (sgn - (sgn >> 15));  // per-half: neg?0xffff:0x8000
      uint32 k = w ^ mskk;                               // packed monotone keys
      if (!real) k = 0u;                                 // pad = strict minimum
      khi[i * 4 + j] = k;
    }
  }

  // 16-sweep 1-bit radix descent for the exact 100th-largest key
  uint32 prefix = 0;
  #pragma unroll 1
  for (int bit = 15; bit >= 0; --bit) {
    uint32 T16 = (prefix | (1u << bit)) << 16;
    int c = 0;
    #pragma unroll
    for (int r = 0; r < 64; ++r) {
      c += (khi[r] >= T16);            // hi-key >= t
      c += ((khi[r] << 16) >= T16);    // lo-key >= t
    }
    #pragma unroll
    for (int m = 1; m < 64; m <<= 1) c += __shfl_xor(c, m, 64);
    if (c >= 100) prefix |= (1u << bit);
  }
  // prefix == T: #{>=T} >= 100, #{>T} <= 99

  // gather strictly-greater keys (<=99), fill ties with T
  #pragma unroll
  for (int r = 0; r < 64; ++r) {
    uint32 h = khi[r] >> 16;
    uint32 l = khi[r] & 0xffffu;
    if (h > prefix) { int p = atomicAdd(&gcnt, 1); cand[p] = h; }
    if (l > prefix) { int p = atomicAdd(&gcnt, 1); cand[p] = l; }
  }
  __syncthreads();
  int cg = gcnt;
  for (int idx = lane; idx < 100; idx += 64)
    if (idx >= cg) cand[idx] = prefix;
  __syncthreads();

  // rank-sort 100 keys (broadcast LDS reads), convert key -> fp32 value
  for (int idx = lane; idx < 100; idx += 64) {
    uint32 ci = cand[idx];
    int rank = 0;
    for (int j = 0; j < 100; ++j) {
      uint32 cj = cand[j];
      rank += (cj > ci) || (cj == ci && j < idx);
    }
    uint32 bb = (ci & 0x8000u) ? (ci & 0x7fffu) : (~ci & 0xffffu);
    sval[rank] = __uint_as_float(bb << 16);
  }
  __syncthreads();

  if (lane == 0) {
    const int KSv[4] = {10, 25, 50, 100};
    float num = 0.f, den = 0.f, pred = 0.f;
    int ki = 0;
    for (int j = 0; j < 100; ++j) {
      num += sval[j] * m100[j];
      den += m100[j];
      if (j + 1 == KSv[ki]) { pred += 0.25f * num / den; ++ki; }
    }
    out[(size_t)b * O_ + o] = pred;
  }
}

// -------------------- launcher ---------------------------------------------------
extern "C" void kernel_launch(void* const* d_in, const int* in_sizes, int n_in,
                              void* d_out, int out_size, void* d_ws, size_t ws_size,
                              hipStream_t stream) {
  const float* x  = (const float*)d_in[0];
  const float* W0 = (const float*)d_in[1];
  const float* b0 = (const float*)d_in[2];
  const float* W1 = (const float*)d_in[3];
  const float* b1 = (const float*)d_in[4];
  const float* W2 = (const float*)d_in[5];
  const float* b2 = (const float*)d_in[6];
  float* out = (float*)d_out;

  char* ws = (char*)d_ws;
  bf16*  W0b  = (bf16*)(ws + 0);          // 1,048,576 B
  bf16*  W1b  = (bf16*)(ws + 1048576);    //   131,072 B
  bf16*  W2b  = (bf16*)(ws + 1179648);    //   524,288 B
  float* mk   = (float*)(ws + 1703936);   //   256,000 B
  bf16*  yb   = (bf16*)(ws + 1959936);    // 131,072,000 B

  castw<<<832, 256, 0, stream>>>(W0, W1, W2, W0b, W1b, W2b);
  gemm123<<<dim3(125, 8), 256, 0, stream>>>(x, W0b, b0, W1b, b1, W2b, b2, mk, yb);
  topk<<<dim3(1000, 8), 64, 0, stream>>>(yb, mk, out);
}